// Round 1
// baseline (154.039 us; speedup 1.0000x reference)
//
#include <hip/hip_runtime.h>

#define EE 1024
#define SS 512
#define NBATCH 16
#define PP 96
#define KK 4
#define NROWS (NBATCH * SS)   // 8192
#define NJ (PP * KK)          // 384
#define EPS 1e-8f

// ---------------- row norms: rn2[r] = sum_e emb[r,e]^2 ----------------
__global__ __launch_bounds__(256) void rownorm_kernel(const float* __restrict__ emb,
                                                      float* __restrict__ rn2) {
    int r = blockIdx.x;
    int t = threadIdx.x;  // 256 threads, one float4 each (1024 floats/row)
    float4 v = ((const float4*)(emb + (size_t)r * EE))[t];
    float s = v.x * v.x + v.y * v.y + v.z * v.z + v.w * v.w;
#pragma unroll
    for (int off = 32; off; off >>= 1) s += __shfl_down(s, off);
    __shared__ float red[4];
    if ((t & 63) == 0) red[t >> 6] = s;
    __syncthreads();
    if (t == 0) rn2[r] = red[0] + red[1] + red[2] + red[3];
}

// ---------------- proto norms: pn[p] = ||proto[p, 0:4096]|| ----------------
__global__ __launch_bounds__(256) void pnorm_kernel(const float* __restrict__ proto,
                                                    float* __restrict__ pn) {
    int p = blockIdx.x;
    int t = threadIdx.x;
    const float4* row = (const float4*)(proto + (size_t)p * 4096);
    float s = 0.f;
#pragma unroll
    for (int i = 0; i < 4; i++) {
        float4 v = row[t + 256 * i];
        s += v.x * v.x + v.y * v.y + v.z * v.z + v.w * v.w;
    }
#pragma unroll
    for (int off = 32; off; off >>= 1) s += __shfl_down(s, off);
    __shared__ float red[4];
    if ((t & 63) == 0) red[t >> 6] = s;
    __syncthreads();
    if (t == 0) pn[p] = sqrtf(red[0] + red[1] + red[2] + red[3]);
}

// ---------------- GEMM: Rt[j, r] = sum_e A[r,e] * B[j,e] ----------------
// A = emb (8192 x 1024), B = proto viewed as (384 x 1024). fp32 VALU.
#define BM 64
#define BN 64
#define BK 16

__global__ __launch_bounds__(256) void gemm_kernel(const float* __restrict__ A,
                                                   const float* __restrict__ B,
                                                   float* __restrict__ Rt) {
    __shared__ float As[BK][BM + 1];
    __shared__ float Bs[BK][BN + 1];
    int bm = blockIdx.x % (NROWS / BM);  // 128
    int bn = blockIdx.x / (NROWS / BM);  // 6
    int r0 = bm * BM, j0 = bn * BN;
    int tid = threadIdx.x;
    int tx = tid % 16, ty = tid / 16;
    int lrow = tid >> 2;          // 0..63
    int lk = (tid & 3) * 4;       // 0,4,8,12

    float acc[4][4] = {};

    for (int k0 = 0; k0 < EE; k0 += BK) {
        float4 av = *(const float4*)(A + (size_t)(r0 + lrow) * EE + k0 + lk);
        float4 bv = *(const float4*)(B + (size_t)(j0 + lrow) * EE + k0 + lk);
        __syncthreads();
        As[lk + 0][lrow] = av.x; As[lk + 1][lrow] = av.y;
        As[lk + 2][lrow] = av.z; As[lk + 3][lrow] = av.w;
        Bs[lk + 0][lrow] = bv.x; Bs[lk + 1][lrow] = bv.y;
        Bs[lk + 2][lrow] = bv.z; Bs[lk + 3][lrow] = bv.w;
        __syncthreads();
#pragma unroll
        for (int kk = 0; kk < BK; kk++) {
            float a[4], b[4];
#pragma unroll
            for (int i = 0; i < 4; i++) a[i] = As[kk][ty * 4 + i];
#pragma unroll
            for (int j = 0; j < 4; j++) b[j] = Bs[kk][tx * 4 + j];
#pragma unroll
            for (int i = 0; i < 4; i++)
#pragma unroll
                for (int j = 0; j < 4; j++) acc[i][j] += a[i] * b[j];
        }
    }
#pragma unroll
    for (int j = 0; j < 4; j++) {
        size_t base = (size_t)(j0 + tx * 4 + j) * NROWS + r0 + ty * 4;
#pragma unroll
        for (int i = 0; i < 4; i++) Rt[base + i] = acc[i][j];
    }
}

// ---------------- combine: min-pool of -cos over window positions ----------------
// dot[n,p,h] = sum_{j=0..3} Rt[(4p+j), n*512 + s(q)]  with q=4h+j,
//   s(q) = (q % H) + (q / H) * d,  H = 512 - 3d,  d = p/32 + 1
__global__ __launch_bounds__(256) void combine_kernel(const float* __restrict__ Rt,
                                                      const float* __restrict__ rn2,
                                                      const float* __restrict__ pn,
                                                      float* __restrict__ out) {
    int wave = threadIdx.x >> 6;
    int lane = threadIdx.x & 63;
    int pair = blockIdx.x * 4 + wave;   // 1536 pairs
    int n = pair / PP;
    int p = pair % PP;
    int g = p >> 5;
    int d = g + 1;
    int H = SS - 3 * d;
    float pnv = fmaxf(pn[p], EPS);
    float best = -3.4e38f;
    for (int h = lane; h < H; h += 64) {
        float dot = 0.f, x2 = 0.f;
#pragma unroll
        for (int j = 0; j < 4; j++) {
            int q = h * 4 + j;
            int k = q / H;
            int s = q - k * H + k * d;
            int r = n * SS + s;
            dot += Rt[(size_t)(4 * p + j) * NROWS + r];
            x2 += rn2[r];
        }
        float xn = fmaxf(sqrtf(x2), EPS);
        float c = dot / (xn * pnv);
        best = fmaxf(best, c);
    }
#pragma unroll
    for (int off = 32; off; off >>= 1) best = fmaxf(best, __shfl_down(best, off));
    if (lane == 0) out[n * PP + p] = -best;
}

// ---------------- tiny FC: class_out[n,c] = sum_p pd[n,p] * fc[c,p] ----------------
__global__ __launch_bounds__(64) void fc_kernel(const float* __restrict__ pd,
                                                const float* __restrict__ fcw,
                                                float* __restrict__ cls) {
    int t = threadIdx.x;
    if (t >= 32) return;
    int n = t >> 1, c = t & 1;
    float s = 0.f;
    for (int p = 0; p < PP; p++) s += pd[n * PP + p] * fcw[c * PP + p];
    cls[n * 2 + c] = s;
}

extern "C" void kernel_launch(void* const* d_in, const int* in_sizes, int n_in,
                              void* d_out, int out_size, void* d_ws, size_t ws_size,
                              hipStream_t stream) {
    const float* emb = (const float*)d_in[0];     // (16,512,1024) f32
    // d_in[1] = mask (unused)
    const float* proto = (const float*)d_in[2];   // (96,1024,4) f32 -> flat (96,4096)
    const float* fcw = (const float*)d_in[3];     // (2,96) f32
    float* out = (float*)d_out;                   // 1536 pd + 32 class

    float* Rt = (float*)d_ws;                         // 384*8192 f32
    float* rn2 = Rt + (size_t)NJ * NROWS;             // 8192 f32
    float* pn = rn2 + NROWS;                          // 96 f32

    rownorm_kernel<<<NROWS, 256, 0, stream>>>(emb, rn2);
    pnorm_kernel<<<PP, 256, 0, stream>>>(proto, pn);
    gemm_kernel<<<(NROWS / BM) * (NJ / BN), 256, 0, stream>>>(emb, proto, Rt);
    combine_kernel<<<NBATCH * PP / 4, 256, 0, stream>>>(Rt, rn2, pn, out);
    fc_kernel<<<1, 64, 0, stream>>>(out, fcw, out + NBATCH * PP);
}

// Round 2
// 53.660 us; speedup vs baseline: 2.8706x; 2.8706x over previous
//
#include <hip/hip_runtime.h>
#include <stdint.h>

#define EE 1024
#define SS 512
#define NBATCH 16
#define PP 96
#define NROWS (NBATCH * SS)   // 8192
#define NJ (PP * 4)           // 384
#define EPS 1e-8f

typedef __attribute__((ext_vector_type(8))) short bf16x8;
typedef __attribute__((ext_vector_type(4))) float f32x4;

// round-to-nearest-even f32 -> bf16 bits
__device__ __forceinline__ ushort f2bf(float f) {
    uint32_t u = __float_as_uint(f);
    u += 0x7fffu + ((u >> 16) & 1u);
    return (ushort)(u >> 16);
}

__device__ __forceinline__ void gload16(const void* g, void* l) {
    __builtin_amdgcn_global_load_lds(
        (const __attribute__((address_space(1))) uint32_t*)g,
        (__attribute__((address_space(3))) uint32_t*)l, 16, 0, 0);
}

// ---- convert emb f32 -> bf16, fused row-norm^2 ----
__global__ __launch_bounds__(256) void conv_emb_kernel(const float* __restrict__ emb,
                                                       ushort* __restrict__ ebf,
                                                       float* __restrict__ rn2) {
    int r = blockIdx.x, t = threadIdx.x;
    float4 v = ((const float4*)(emb + (size_t)r * EE))[t];
    ((ushort4*)(ebf + (size_t)r * EE))[t] =
        make_ushort4(f2bf(v.x), f2bf(v.y), f2bf(v.z), f2bf(v.w));
    float s = v.x * v.x + v.y * v.y + v.z * v.z + v.w * v.w;
#pragma unroll
    for (int off = 32; off; off >>= 1) s += __shfl_down(s, off);
    __shared__ float red[4];
    if ((t & 63) == 0) red[t >> 6] = s;
    __syncthreads();
    if (t == 0) rn2[r] = red[0] + red[1] + red[2] + red[3];
}

// ---- convert proto f32 -> bf16, fused proto norm ----
__global__ __launch_bounds__(256) void conv_proto_kernel(const float* __restrict__ proto,
                                                         ushort* __restrict__ pbf,
                                                         float* __restrict__ pn) {
    int p = blockIdx.x, t = threadIdx.x;
    const float4* src = (const float4*)(proto + (size_t)p * 4096);
    ushort4* dst = (ushort4*)(pbf + (size_t)p * 4096);
    float s = 0.f;
#pragma unroll
    for (int i = 0; i < 4; i++) {
        float4 v = src[t + 256 * i];
        dst[t + 256 * i] = make_ushort4(f2bf(v.x), f2bf(v.y), f2bf(v.z), f2bf(v.w));
        s += v.x * v.x + v.y * v.y + v.z * v.z + v.w * v.w;
    }
#pragma unroll
    for (int off = 32; off; off >>= 1) s += __shfl_down(s, off);
    __shared__ float red[4];
    if ((t & 63) == 0) red[t >> 6] = s;
    __syncthreads();
    if (t == 0) pn[p] = sqrtf(red[0] + red[1] + red[2] + red[3]);
}

// ---- bf16 MFMA GEMM: Rt[split][j][r] = sum_{k in split} A[r,k]*B[j,k] ----
#define GBM 128
#define GBN 128
#define GBK 32

__global__ __launch_bounds__(256) void gemm_kernel(const ushort* __restrict__ A,
                                                   const ushort* __restrict__ B,
                                                   float* __restrict__ Rt,
                                                   int nsplit) {
    __shared__ ushort As[GBM * GBK];
    __shared__ ushort Bs[GBN * GBK];
    const int per = (NROWS / GBM) * (NJ / GBN);  // 64*3 = 192
    int bid = blockIdx.x;
    int split = bid / per;
    int rem = bid - split * per;
    int bm = rem & 63;        // NROWS/GBM = 64
    int bn = rem >> 6;        // 0..2
    int klen = EE / nsplit;
    int kb = split * klen;
    int r0 = bm * GBM, j0 = bn * GBN;
    int tid = threadIdx.x;
    int lane = tid & 63;

    // staging: thread t -> LDS linear byte t*16 (= row t/4, chunk t&3 of 32-elem row)
    // pre-swizzled global chunk: c ^ (row & 3)
    int srow = tid >> 2;
    int schunk = (tid & 3) ^ (srow & 3);
    const ushort* ga = A + (size_t)(r0 + srow) * EE + kb + schunk * 8;
    const ushort* gb = B + (size_t)(j0 + srow) * EE + kb + schunk * 8;
    ushort* lA = As + tid * 8;
    ushort* lB = Bs + tid * 8;

    int w = tid >> 6;
    int wm = (w >> 1) * 64, wn = (w & 1) * 64;
    int kc = lane >> 4;       // k-chunk 0..3
    int fr = lane & 15;       // fragment row/col
    int fchunk = kc ^ (fr & 3);  // swizzled read chunk

    f32x4 acc[4][4] = {};

    for (int k0 = 0; k0 < klen; k0 += GBK) {
        __syncthreads();
        gload16(ga + k0, lA);
        gload16(ga + 64 * EE + k0, lA + 2048);
        gload16(gb + k0, lB);
        gload16(gb + 64 * EE + k0, lB + 2048);
        __syncthreads();
        bf16x8 af[4], bfr[4];
#pragma unroll
        for (int m = 0; m < 4; m++)
            af[m] = *(const bf16x8*)(As + (wm + m * 16 + fr) * GBK + fchunk * 8);
#pragma unroll
        for (int n = 0; n < 4; n++)
            bfr[n] = *(const bf16x8*)(Bs + (wn + n * 16 + fr) * GBK + fchunk * 8);
#pragma unroll
        for (int m = 0; m < 4; m++)
#pragma unroll
            for (int n = 0; n < 4; n++)
                acc[m][n] = __builtin_amdgcn_mfma_f32_16x16x32_bf16(af[m], bfr[n], acc[m][n], 0, 0, 0);
    }

    float* Rbase = Rt + (size_t)split * NJ * NROWS;
    int rloc = r0 + wm + (lane >> 4) * 4;
    int jloc = j0 + wn + fr;
#pragma unroll
    for (int m = 0; m < 4; m++)
#pragma unroll
        for (int n = 0; n < 4; n++)
            *(f32x4*)(Rbase + (size_t)(jloc + n * 16) * NROWS + rloc + m * 16) = acc[m][n];
}

// ---- combine: min-pool of -cos over window positions ----
__global__ __launch_bounds__(256) void combine_kernel(const float* __restrict__ Rt,
                                                      const float* __restrict__ rn2,
                                                      const float* __restrict__ pn,
                                                      float* __restrict__ out, int nsplit) {
    int wave = threadIdx.x >> 6;
    int lane = threadIdx.x & 63;
    int pair = blockIdx.x * 4 + wave;   // 1536 pairs
    int n = pair / PP;
    int p = pair % PP;
    int d = (p >> 5) + 1;
    int H = SS - 3 * d;
    float pnv = fmaxf(pn[p], EPS);
    float best = -3.4e38f;
    for (int h = lane; h < H; h += 64) {
        float dot = 0.f, x2 = 0.f;
#pragma unroll
        for (int j = 0; j < 4; j++) {
            int q = h * 4 + j;
            int k = q / H;
            int s = q - k * H + k * d;
            int r = n * SS + s;
            size_t off = (size_t)(4 * p + j) * NROWS + r;
            float dv = Rt[off];
            if (nsplit == 2) dv += Rt[(size_t)NJ * NROWS + off];
            dot += dv;
            x2 += rn2[r];
        }
        float xn = fmaxf(sqrtf(x2), EPS);
        best = fmaxf(best, dot / (xn * pnv));
    }
#pragma unroll
    for (int off = 32; off; off >>= 1) best = fmaxf(best, __shfl_down(best, off));
    if (lane == 0) out[n * PP + p] = -best;
}

// ---- tiny FC ----
__global__ __launch_bounds__(64) void fc_kernel(const float* __restrict__ pd,
                                                const float* __restrict__ fcw,
                                                float* __restrict__ cls) {
    int t = threadIdx.x;
    if (t >= 32) return;
    int n = t >> 1, c = t & 1;
    float s = 0.f;
    for (int p = 0; p < PP; p++) s += pd[n * PP + p] * fcw[c * PP + p];
    cls[n * 2 + c] = s;
}

extern "C" void kernel_launch(void* const* d_in, const int* in_sizes, int n_in,
                              void* d_out, int out_size, void* d_ws, size_t ws_size,
                              hipStream_t stream) {
    const float* emb = (const float*)d_in[0];     // (16,512,1024) f32
    const float* proto = (const float*)d_in[2];   // (96,1024,4) f32 flat = (384,1024)
    const float* fcw = (const float*)d_in[3];     // (2,96)
    float* out = (float*)d_out;

    uint8_t* ws = (uint8_t*)d_ws;
    ushort* ebf = (ushort*)ws;                                   // 16 MB
    ushort* pbf = (ushort*)(ws + (size_t)NROWS * EE * 2);        // 0.75 MB
    float* rn2 = (float*)(ws + (size_t)NROWS * EE * 2 + (size_t)NJ * EE * 2);
    float* pn = rn2 + NROWS;
    float* Rt = pn + 128;  // 16B-aligned
    size_t fixed = (size_t)NROWS * EE * 2 + (size_t)NJ * EE * 2 + (size_t)(NROWS + 128) * 4;
    int nsplit = (ws_size >= fixed + 2 * (size_t)NJ * NROWS * 4) ? 2 : 1;

    conv_emb_kernel<<<NROWS, 256, 0, stream>>>(emb, ebf, rn2);
    conv_proto_kernel<<<PP, 256, 0, stream>>>(proto, pbf, pn);
    gemm_kernel<<<192 * nsplit, 256, 0, stream>>>(ebf, pbf, Rt, nsplit);
    combine_kernel<<<NBATCH * PP / 4, 256, 0, stream>>>(Rt, rn2, pn, out, nsplit);
    fc_kernel<<<1, 64, 0, stream>>>(out, fcw, out + NBATCH * PP);
}